// Round 17
// baseline (393.244 us; speedup 1.0000x reference)
//
#include <hip/hip_runtime.h>
#include <hip/hip_fp16.h>
#include <math.h>

#define NQ 14
#define NL 6
#define NT 512
#define NGATES (NL * NQ)
#define NK 16   // half2 regs per re/im = 32 amps/thread
// amp p = (tid<<5) | j, j=0..31. j bits 0-3 = reg k, j bit 4 = packing bit.
// amp bit map: p<4 local k-bit; p==4 packing (cross-half fp32);
// 5<=p<11 lane bit (tid bit p-5); p>=11 wave bit (tid bits 6..8).
// Wire w <-> P = 13-w: wires 0-2 wave, 3-8 lane, 9 packing, 10-13 local.
// R17: 32 KB exchange buffer (full-state wave exchanges in 2 half phases)
// -> 4 blocks/CU (32 waves, 100% occupancy at 60 VGPRs). Extra barriers are
// hidden by cross-block overlap. Flat arrays only (R15 lesson).

using F4 = float4;
using H2 = __half2;

__device__ __forceinline__ unsigned h2u(H2 v){ return __builtin_bit_cast(unsigned, v); }
__device__ __forceinline__ H2 u2h(unsigned x){ return __builtin_bit_cast(H2, x); }
__device__ __forceinline__ float h2f(H2 v){ return __builtin_bit_cast(float, v); }
__device__ __forceinline__ H2 f2h(float x){ return __builtin_bit_cast(H2, x); }
__device__ __forceinline__ float uf(unsigned x){ return __builtin_bit_cast(float, x); }
__device__ __forceinline__ unsigned fu(float x){ return __builtin_bit_cast(unsigned, x); }
__device__ __forceinline__ H2 bc(float x){ return __float2half2_rn(x); }
__device__ __forceinline__ H2 shflx(H2 v, int m){
    return u2h((unsigned)__shfl_xor((int)h2u(v), m, 64));
}

// ---- prep: Rot matrices (batch-shared, fp32) into d_ws ----
__global__ void prep_kernel(const float* __restrict__ wts, float* __restrict__ gm) {
    int g = blockIdx.x * blockDim.x + threadIdx.x;
    if (g < NGATES) {
        float phi = wts[g*3+0], th = wts[g*3+1], om = wts[g*3+2];
        float c = cosf(0.5f*th), s = sinf(0.5f*th);
        float a = 0.5f*(phi+om), bb = 0.5f*(phi-om);
        float ca = cosf(a), sa = sinf(a);
        float cb = cosf(bb), sb = sinf(bb);
        gm[g*8+0] = c*ca;  gm[g*8+1] = -c*sa;   // m00
        gm[g*8+2] = -s*cb; gm[g*8+3] = -s*sb;   // m01
        gm[g*8+4] = s*cb;  gm[g*8+5] = -s*sb;   // m10
        gm[g*8+6] = c*ca;  gm[g*8+7] = c*sa;    // m11
    }
}

// ---- Rot on amp bit P ----
template<int P>
__device__ __forceinline__ void rot_gate(H2 (&pr)[NK], H2 (&pi)[NK],
                                         const float* __restrict__ m, int tid, F4* buf) {
    float m0=m[0],m1=m[1],m2=m[2],m3=m[3],m4=m[4],m5=m[5],m6=m[6],m7=m[7];
    if constexpr (P < 4) {
        constexpr int M = 1 << P;
        H2 h0=bc(m0),h1=bc(m1),nh1=bc(-m1),h2v=bc(m2),h3=bc(m3),nh3=bc(-m3);
        H2 h4=bc(m4),h5=bc(m5),nh5=bc(-m5),h6=bc(m6),h7=bc(m7),nh7=bc(-m7);
        #pragma unroll
        for (int i = 0; i < NK/2; ++i) {
            int k0 = ((i >> P) << (P+1)) | (i & (M-1));
            int k1 = k0 | M;
            H2 r0=pr[k0], i0=pi[k0], r1=pr[k1], i1=pi[k1];
            pr[k0] = __hfma2(h0,r0,__hfma2(nh1,i0,__hfma2(h2v,r1,__hmul2(nh3,i1))));
            pi[k0] = __hfma2(h0,i0,__hfma2(h1,r0,__hfma2(h2v,i1,__hmul2(h3,r1))));
            pr[k1] = __hfma2(h4,r0,__hfma2(nh5,i0,__hfma2(h6,r1,__hmul2(nh7,i1))));
            pi[k1] = __hfma2(h4,i0,__hfma2(h5,r0,__hfma2(h6,i1,__hmul2(h7,r1))));
        }
    } else if constexpr (P == 4) {
        // cross-half (packing bit): fp32 math per reg
        #pragma unroll
        for (int k = 0; k < NK; ++k) {
            float r0=__low2float(pr[k]), r1=__high2float(pr[k]);
            float i0=__low2float(pi[k]), i1=__high2float(pi[k]);
            float lr = m0*r0 - m1*i0 + m2*r1 - m3*i1;
            float li = m0*i0 + m1*r0 + m2*i1 + m3*r1;
            float hr = m4*r0 - m5*i0 + m6*r1 - m7*i1;
            float hi = m4*i0 + m5*r0 + m6*i1 + m7*r1;
            pr[k] = __floats2half2_rn(lr, hr);
            pi[k] = __floats2half2_rn(li, hi);
        }
    } else if constexpr (P < 11) {
        constexpr int LM = 1 << (P-5);
        int bit = (tid >> (P-5)) & 1;
        float cAr = bit ? m6 : m0, cAi = bit ? m7 : m1;
        float cBr = bit ? m4 : m2, cBi = bit ? m5 : m3;
        H2 a=bc(cAr), ai2=bc(cAi), nai=bc(-cAi), b2=bc(cBr), bi2=bc(cBi), nbi=bc(-cBi);
        #pragma unroll
        for (int k = 0; k < NK; ++k) {
            H2 r = pr[k], i = pi[k];
            H2 qr = shflx(r, LM), qi = shflx(i, LM);
            pr[k] = __hfma2(a,r,__hfma2(nai,i,__hfma2(b2,qr,__hmul2(nbi,qi))));
            pi[k] = __hfma2(a,i,__hfma2(ai2,r,__hfma2(b2,qi,__hmul2(bi2,qr))));
        }
    } else {
        constexpr int WM = 1 << (P-5);
        int ptid = tid ^ WM;
        int bit = (tid >> (P-5)) & 1;
        float cAr = bit ? m6 : m0, cAi = bit ? m7 : m1;
        float cBr = bit ? m4 : m2, cBi = bit ? m5 : m3;
        H2 a=bc(cAr), ai2=bc(cAi), nai=bc(-cAi), b2=bc(cBr), bi2=bc(cBi), nbi=bc(-cBi);
        // half-state per phase (2 F4 pr + 2 F4 pi) -> 32 KB buffer
        #pragma unroll
        for (int h = 0; h < 2; ++h) {
            int base = 8*h;
            buf[0*NT + tid] = make_float4(h2f(pr[base]),  h2f(pr[base+1]),h2f(pr[base+2]),h2f(pr[base+3]));
            buf[1*NT + tid] = make_float4(h2f(pr[base+4]),h2f(pr[base+5]),h2f(pr[base+6]),h2f(pr[base+7]));
            buf[2*NT + tid] = make_float4(h2f(pi[base]),  h2f(pi[base+1]),h2f(pi[base+2]),h2f(pi[base+3]));
            buf[3*NT + tid] = make_float4(h2f(pi[base+4]),h2f(pi[base+5]),h2f(pi[base+6]),h2f(pi[base+7]));
            __syncthreads();
            F4 a0 = buf[0*NT+ptid], a1 = buf[1*NT+ptid];
            F4 b0 = buf[2*NT+ptid], b1 = buf[3*NT+ptid];
            H2 qr[8] = {f2h(a0.x),f2h(a0.y),f2h(a0.z),f2h(a0.w),
                        f2h(a1.x),f2h(a1.y),f2h(a1.z),f2h(a1.w)};
            H2 qi[8] = {f2h(b0.x),f2h(b0.y),f2h(b0.z),f2h(b0.w),
                        f2h(b1.x),f2h(b1.y),f2h(b1.z),f2h(b1.w)};
            #pragma unroll
            for (int q = 0; q < 8; ++q) {
                int k = base + q;
                H2 r = pr[k], i = pi[k];
                pr[k] = __hfma2(a,r,__hfma2(nai,i,__hfma2(b2,qr[q],__hmul2(nbi,qi[q]))));
                pi[k] = __hfma2(a,i,__hfma2(ai2,r,__hfma2(b2,qi[q],__hmul2(bi2,qr[q]))));
            }
            __syncthreads();
        }
    }
}

// ---- CNOT(ctrl bit PC, target bit PT) ----
template<int PC, int PT>
__device__ __forceinline__ void cnot_gate(H2 (&pr)[NK], H2 (&pi)[NK], int tid, F4* buf) {
    if constexpr (PT < 4) {
        constexpr int TM = 1 << PT;
        if constexpr (PC < 4) {
            constexpr int CM = 1 << PC;
            #pragma unroll
            for (int k = 0; k < NK; ++k)
                if ((k & CM) && !(k & TM)) {
                    int k1 = k | TM;
                    H2 t = pr[k]; pr[k] = pr[k1]; pr[k1] = t;
                    t = pi[k]; pi[k] = pi[k1]; pi[k1] = t;
                }
        } else if constexpr (PC == 4) {
            // ctrl = packing bit: swap only hi halves of (k, k|TM)
            #pragma unroll
            for (int k = 0; k < NK; ++k)
                if (!(k & TM)) {
                    int k1 = k | TM;
                    unsigned A = h2u(pr[k]), B = h2u(pr[k1]);
                    pr[k]  = u2h((A & 0xFFFFu) | (B & 0xFFFF0000u));
                    pr[k1] = u2h((B & 0xFFFFu) | (A & 0xFFFF0000u));
                    A = h2u(pi[k]); B = h2u(pi[k1]);
                    pi[k]  = u2h((A & 0xFFFFu) | (B & 0xFFFF0000u));
                    pi[k1] = u2h((B & 0xFFFFu) | (A & 0xFFFF0000u));
                }
        } else {
            int sel = (tid >> (PC-5)) & 1;
            #pragma unroll
            for (int k = 0; k < NK; ++k)
                if (!(k & TM)) {
                    int k1 = k | TM;
                    H2 A = pr[k], B = pr[k1];
                    pr[k] = sel ? B : A; pr[k1] = sel ? A : B;
                    A = pi[k]; B = pi[k1];
                    pi[k] = sel ? B : A; pi[k1] = sel ? A : B;
                }
        }
    } else if constexpr (PT == 4) {
        // target = packing bit: swap halves where ctrl==1
        if constexpr (PC < 4) {
            constexpr int CM = 1 << PC;
            #pragma unroll
            for (int k = 0; k < NK; ++k)
                if (k & CM) {
                    unsigned A = h2u(pr[k]); pr[k] = u2h((A>>16)|(A<<16));
                    A = h2u(pi[k]); pi[k] = u2h((A>>16)|(A<<16));
                }
        } else {
            int sel = (tid >> (PC-5)) & 1;
            #pragma unroll
            for (int k = 0; k < NK; ++k) {
                unsigned A = h2u(pr[k]), S = (A>>16)|(A<<16);
                pr[k] = u2h(sel ? S : A);
                A = h2u(pi[k]); S = (A>>16)|(A<<16);
                pi[k] = u2h(sel ? S : A);
            }
        }
    } else if constexpr (PT < 11) {
        constexpr int LM = 1 << (PT-5);
        if constexpr (PC < 4) {
            constexpr int CM = 1 << PC;
            #pragma unroll
            for (int k = 0; k < NK; ++k)
                if (k & CM) { pr[k] = shflx(pr[k], LM); pi[k] = shflx(pi[k], LM); }
        } else if constexpr (PC == 4) {
            // ctrl = packing bit: only hi halves exchange between partner lanes
            #pragma unroll
            for (int k = 0; k < NK; ++k) {
                unsigned S = h2u(shflx(pr[k], LM));
                pr[k] = u2h((h2u(pr[k]) & 0xFFFFu) | (S & 0xFFFF0000u));
                S = h2u(shflx(pi[k], LM));
                pi[k] = u2h((h2u(pi[k]) & 0xFFFFu) | (S & 0xFFFF0000u));
            }
        } else {
            // ctrl thread bit != PT: partner has same sel -> conditional shuffle
            int sel = (tid >> (PC-5)) & 1;
            #pragma unroll
            for (int k = 0; k < NK; ++k) {
                H2 sr = shflx(pr[k], LM), si = shflx(pi[k], LM);
                pr[k] = sel ? sr : pr[k];
                pi[k] = sel ? si : pi[k];
            }
        }
    } else {
        constexpr int WM = 1 << (PT-5);
        int ptid = tid ^ WM;
        if constexpr (PC < 4) {
            constexpr int CM = 1 << PC;
            // exchange only the 8 ctrl==1 regs (2 F4 pr + 2 F4 pi), one phase
            H2 vr[8], vi[8];
            { int c = 0;
              #pragma unroll
              for (int k = 0; k < NK; ++k)
                  if (k & CM) { vr[c]=pr[k]; vi[c]=pi[k]; ++c; } }
            buf[0*NT+tid] = make_float4(h2f(vr[0]),h2f(vr[1]),h2f(vr[2]),h2f(vr[3]));
            buf[1*NT+tid] = make_float4(h2f(vr[4]),h2f(vr[5]),h2f(vr[6]),h2f(vr[7]));
            buf[2*NT+tid] = make_float4(h2f(vi[0]),h2f(vi[1]),h2f(vi[2]),h2f(vi[3]));
            buf[3*NT+tid] = make_float4(h2f(vi[4]),h2f(vi[5]),h2f(vi[6]),h2f(vi[7]));
            __syncthreads();
            F4 a0 = buf[0*NT+ptid], a1 = buf[1*NT+ptid];
            F4 b0 = buf[2*NT+ptid], b1 = buf[3*NT+ptid];
            H2 wr[8] = {f2h(a0.x),f2h(a0.y),f2h(a0.z),f2h(a0.w),
                        f2h(a1.x),f2h(a1.y),f2h(a1.z),f2h(a1.w)};
            H2 wi[8] = {f2h(b0.x),f2h(b0.y),f2h(b0.z),f2h(b0.w),
                        f2h(b1.x),f2h(b1.y),f2h(b1.z),f2h(b1.w)};
            { int c = 0;
              #pragma unroll
              for (int k = 0; k < NK; ++k)
                  if (k & CM) { pr[k]=wr[c]; pi[k]=wi[c]; ++c; } }
            __syncthreads();
        } else if constexpr (PC == 4) {
            // ctrl = packing bit: hi halves exchange with partner thread (4 F4)
            unsigned er[8], ei[8];
            #pragma unroll
            for (int t = 0; t < 8; ++t) {
                er[t] = (h2u(pr[2*t]) >> 16) | (h2u(pr[2*t+1]) & 0xFFFF0000u);
                ei[t] = (h2u(pi[2*t]) >> 16) | (h2u(pi[2*t+1]) & 0xFFFF0000u);
            }
            buf[0*NT+tid] = make_float4(uf(er[0]),uf(er[1]),uf(er[2]),uf(er[3]));
            buf[1*NT+tid] = make_float4(uf(er[4]),uf(er[5]),uf(er[6]),uf(er[7]));
            buf[2*NT+tid] = make_float4(uf(ei[0]),uf(ei[1]),uf(ei[2]),uf(ei[3]));
            buf[3*NT+tid] = make_float4(uf(ei[4]),uf(ei[5]),uf(ei[6]),uf(ei[7]));
            __syncthreads();
            F4 a0 = buf[0*NT+ptid], a1 = buf[1*NT+ptid];
            F4 b0 = buf[2*NT+ptid], b1 = buf[3*NT+ptid];
            unsigned fr[8] = {fu(a0.x),fu(a0.y),fu(a0.z),fu(a0.w),
                              fu(a1.x),fu(a1.y),fu(a1.z),fu(a1.w)};
            unsigned fi[8] = {fu(b0.x),fu(b0.y),fu(b0.z),fu(b0.w),
                              fu(b1.x),fu(b1.y),fu(b1.z),fu(b1.w)};
            #pragma unroll
            for (int t = 0; t < 8; ++t) {
                pr[2*t]   = u2h((h2u(pr[2*t])   & 0xFFFFu) | (fr[t] << 16));
                pr[2*t+1] = u2h((h2u(pr[2*t+1]) & 0xFFFFu) | (fr[t] & 0xFFFF0000u));
                pi[2*t]   = u2h((h2u(pi[2*t])   & 0xFFFFu) | (fi[t] << 16));
                pi[2*t+1] = u2h((h2u(pi[2*t+1]) & 0xFFFFu) | (fi[t] & 0xFFFF0000u));
            }
            __syncthreads();
        } else {
            // ctrl thread bit != PT: sel==1 threads swap full state, 2 half phases
            int sel = (tid >> (PC-5)) & 1;
            #pragma unroll
            for (int h = 0; h < 2; ++h) {
                int base = 8*h;
                if (sel) {
                    buf[0*NT+tid] = make_float4(h2f(pr[base]),  h2f(pr[base+1]),h2f(pr[base+2]),h2f(pr[base+3]));
                    buf[1*NT+tid] = make_float4(h2f(pr[base+4]),h2f(pr[base+5]),h2f(pr[base+6]),h2f(pr[base+7]));
                    buf[2*NT+tid] = make_float4(h2f(pi[base]),  h2f(pi[base+1]),h2f(pi[base+2]),h2f(pi[base+3]));
                    buf[3*NT+tid] = make_float4(h2f(pi[base+4]),h2f(pi[base+5]),h2f(pi[base+6]),h2f(pi[base+7]));
                }
                __syncthreads();
                if (sel) {
                    F4 a0 = buf[0*NT+ptid], a1 = buf[1*NT+ptid];
                    F4 b0 = buf[2*NT+ptid], b1 = buf[3*NT+ptid];
                    pr[base]  =f2h(a0.x); pr[base+1]=f2h(a0.y); pr[base+2]=f2h(a0.z); pr[base+3]=f2h(a0.w);
                    pr[base+4]=f2h(a1.x); pr[base+5]=f2h(a1.y); pr[base+6]=f2h(a1.z); pr[base+7]=f2h(a1.w);
                    pi[base]  =f2h(b0.x); pi[base+1]=f2h(b0.y); pi[base+2]=f2h(b0.z); pi[base+3]=f2h(b0.w);
                    pi[base+4]=f2h(b1.x); pi[base+5]=f2h(b1.y); pi[base+6]=f2h(b1.z); pi[base+7]=f2h(b1.w);
                }
                __syncthreads();
            }
        }
    }
}

// ---- compile-time circuit drivers ----
template<int L, int W>
__device__ __forceinline__ void do_rots(H2 (&pr)[NK], H2 (&pi)[NK],
                                        const float* __restrict__ gm, int tid, F4* buf) {
    rot_gate<13-W>(pr, pi, gm + (L*NQ + W)*8, tid, buf);
    if constexpr (W < NQ-1) do_rots<L, W+1>(pr, pi, gm, tid, buf);
}

template<int L, int W>
__device__ __forceinline__ void do_cnots(H2 (&pr)[NK], H2 (&pi)[NK], int tid, F4* buf) {
    constexpr int R = (L % (NQ-1)) + 1;
    constexpr int TW = (W + R) % NQ;
    cnot_gate<13-W, 13-TW>(pr, pi, tid, buf);
    if constexpr (W < NQ-1) do_cnots<L, W+1>(pr, pi, tid, buf);
}

template<int L>
__device__ __forceinline__ void do_layer(H2 (&pr)[NK], H2 (&pi)[NK],
                                         const float* __restrict__ gm, int tid, F4* buf) {
    do_rots<L, 0>(pr, pi, gm, tid, buf);
    do_cnots<L, 0>(pr, pi, tid, buf);
    if constexpr (L < NL-1) do_layer<L+1>(pr, pi, gm, tid, buf);
}

__global__ void __launch_bounds__(NT)
qsim_kernel(
    const float* __restrict__ x,
    const float* __restrict__ gm,
    float* __restrict__ out)
{
    __shared__ F4 buf[4 * NT];   // static 32 KB -> 4 blocks/CU (32 waves)
    const int tid = threadIdx.x;
    const int b = blockIdx.x;
    const float* xb = x + b * NQ;

    // ---- direct product-state init (fp32 math, pack to fp16) ----
    H2 pr[NK], pi[NK];
    {
        float cr = 1.f, ci = 0.f;
        #pragma unroll
        for (int bb = 0; bb < 9; ++bb) {       // tid bit bb = amp bit 5+bb = wire 8-bb
            float t = xb[8 - bb];
            float c = cosf(0.5f*t), s = sinf(0.5f*t);
            if ((tid >> bb) & 1) { float nr = s*ci, ni = -s*cr; cr = nr; ci = ni; }
            else                 { cr *= c; ci *= c; }
        }
        float lc[4], ls[4];                     // k bit bb = wire 13-bb
        #pragma unroll
        for (int bb = 0; bb < 4; ++bb) {
            float t = xb[13 - bb];
            lc[bb] = cosf(0.5f*t); ls[bb] = sinf(0.5f*t);
        }
        float c9 = cosf(0.5f*xb[9]), s9 = sinf(0.5f*xb[9]);   // packing bit = wire 9
        #pragma unroll
        for (int k = 0; k < NK; ++k) {
            float rr = cr, ii = ci;
            #pragma unroll
            for (int bb = 0; bb < 4; ++bb) {
                if ((k >> bb) & 1) { float nr = ls[bb]*ii, ni = -ls[bb]*rr; rr = nr; ii = ni; }
                else               { rr *= lc[bb]; ii *= lc[bb]; }
            }
            pr[k] = __floats2half2_rn(rr*c9,  s9*ii);
            pi[k] = __floats2half2_rn(ii*c9, -s9*rr);
        }
    }
    __syncthreads();

    do_layer<0>(pr, pi, gm, tid, buf);

    // <Z0>: amp bit 13 = tid bit 8 -> sign uniform per thread
    float acc = 0.f;
    #pragma unroll
    for (int k = 0; k < NK; ++k) {
        float a=__low2float(pr[k]), c=__high2float(pr[k]);
        float d=__low2float(pi[k]), e=__high2float(pi[k]);
        acc += a*a + c*c + d*d + e*e;
    }
    if (tid & 256) acc = -acc;
    #pragma unroll
    for (int off = 32; off > 0; off >>= 1) acc += __shfl_down(acc, off, 64);
    __syncthreads();
    float* f = (float*)buf;
    if ((tid & 63) == 0) f[tid >> 6] = acc;
    __syncthreads();
    if (tid == 0) {
        float s = 0.f;
        #pragma unroll
        for (int w = 0; w < NT/64; ++w) s += f[w];
        out[b] = s;
    }
}

extern "C" void kernel_launch(void* const* d_in, const int* in_sizes, int n_in,
                              void* d_out, int out_size, void* d_ws, size_t ws_size,
                              hipStream_t stream) {
    const float* x = (const float*)d_in[0];   // (1024, 14) float32
    const float* w = (const float*)d_in[1];   // (6, 14, 3) float32
    float* out = (float*)d_out;               // (1024,) float32
    float* gm = (float*)d_ws;                 // 84*8 floats of Rot matrices

    prep_kernel<<<1, 128, 0, stream>>>(w, gm);
    qsim_kernel<<<out_size, NT, 0, stream>>>(x, gm, out);
}

// Round 18
// 382.858 us; speedup vs baseline: 1.0271x; 1.0271x over previous
//
#include <hip/hip_runtime.h>
#include <hip/hip_fp16.h>
#include <math.h>

#define NQ 14
#define NL 6
#define NT 512
#define NGATES (NL * NQ)
#define NK 16   // half2 regs per re/im = 32 amps/thread
// amp p = (tid<<5) | j, j=0..31. j bits 0-3 = reg k, j bit 4 = packing bit.
// amp bit map: p<4 local k-bit; p==4 packing (now fully packed via half-swap);
// 5<=p<11 lane bit (tid bit p-5); p>=11 wave bit (tid bits 6..8).
// Wire w <-> P = 13-w: wires 0-2 wave, 3-8 lane, 9 packing, 10-13 local.
// R18: wire-9 rot done in packed fp16 (half-swap + per-half coeff H2s)
// instead of fp32 unpack -> ~12 fewer insts/reg on 6 gates.

using F4 = float4;
using H2 = __half2;

__device__ __forceinline__ unsigned h2u(H2 v){ return __builtin_bit_cast(unsigned, v); }
__device__ __forceinline__ H2 u2h(unsigned x){ return __builtin_bit_cast(H2, x); }
__device__ __forceinline__ float h2f(H2 v){ return __builtin_bit_cast(float, v); }
__device__ __forceinline__ H2 f2h(float x){ return __builtin_bit_cast(H2, x); }
__device__ __forceinline__ float uf(unsigned x){ return __builtin_bit_cast(float, x); }
__device__ __forceinline__ unsigned fu(float x){ return __builtin_bit_cast(unsigned, x); }
__device__ __forceinline__ H2 bc(float x){ return __float2half2_rn(x); }
__device__ __forceinline__ H2 shflx(H2 v, int m){
    return u2h((unsigned)__shfl_xor((int)h2u(v), m, 64));
}

// ---- prep: Rot matrices (batch-shared, fp32) into d_ws ----
__global__ void prep_kernel(const float* __restrict__ wts, float* __restrict__ gm) {
    int g = blockIdx.x * blockDim.x + threadIdx.x;
    if (g < NGATES) {
        float phi = wts[g*3+0], th = wts[g*3+1], om = wts[g*3+2];
        float c = cosf(0.5f*th), s = sinf(0.5f*th);
        float a = 0.5f*(phi+om), bb = 0.5f*(phi-om);
        float ca = cosf(a), sa = sinf(a);
        float cb = cosf(bb), sb = sinf(bb);
        gm[g*8+0] = c*ca;  gm[g*8+1] = -c*sa;   // m00
        gm[g*8+2] = -s*cb; gm[g*8+3] = -s*sb;   // m01
        gm[g*8+4] = s*cb;  gm[g*8+5] = -s*sb;   // m10
        gm[g*8+6] = c*ca;  gm[g*8+7] = c*sa;    // m11
    }
}

// ---- Rot on amp bit P ----
template<int P>
__device__ __forceinline__ void rot_gate(H2 (&pr)[NK], H2 (&pi)[NK],
                                         const float* __restrict__ m, int tid, F4* buf) {
    float m0=m[0],m1=m[1],m2=m[2],m3=m[3],m4=m[4],m5=m[5],m6=m[6],m7=m[7];
    if constexpr (P < 4) {
        constexpr int M = 1 << P;
        H2 h0=bc(m0),h1=bc(m1),nh1=bc(-m1),h2v=bc(m2),h3=bc(m3),nh3=bc(-m3);
        H2 h4=bc(m4),h5=bc(m5),nh5=bc(-m5),h6=bc(m6),h7=bc(m7),nh7=bc(-m7);
        #pragma unroll
        for (int i = 0; i < NK/2; ++i) {
            int k0 = ((i >> P) << (P+1)) | (i & (M-1));
            int k1 = k0 | M;
            H2 r0=pr[k0], i0=pi[k0], r1=pr[k1], i1=pi[k1];
            pr[k0] = __hfma2(h0,r0,__hfma2(nh1,i0,__hfma2(h2v,r1,__hmul2(nh3,i1))));
            pi[k0] = __hfma2(h0,i0,__hfma2(h1,r0,__hfma2(h2v,i1,__hmul2(h3,r1))));
            pr[k1] = __hfma2(h4,r0,__hfma2(nh5,i0,__hfma2(h6,r1,__hmul2(nh7,i1))));
            pi[k1] = __hfma2(h4,i0,__hfma2(h5,r0,__hfma2(h6,i1,__hmul2(h7,r1))));
        }
    } else if constexpr (P == 4) {
        // packing-bit rot, fully packed: own=(lo,hi), swapped=(hi,lo);
        // lo' = m00*lo + m01*hi ; hi' = m10*lo + m11*hi
        // coefA=(m00,m11) on own; coefB=(m01,m10) on swapped.
        H2 cAr = __floats2half2_rn(m0, m6), cAi = __floats2half2_rn(m1, m7);
        H2 nAi = __floats2half2_rn(-m1,-m7);
        H2 cBr = __floats2half2_rn(m2, m4), cBi = __floats2half2_rn(m3, m5);
        H2 nBi = __floats2half2_rn(-m3,-m5);
        #pragma unroll
        for (int k = 0; k < NK; ++k) {
            unsigned Ar = h2u(pr[k]), Ai = h2u(pi[k]);
            H2 sr = u2h((Ar>>16)|(Ar<<16)), si = u2h((Ai>>16)|(Ai<<16));
            H2 r = pr[k], i = pi[k];
            pr[k] = __hfma2(cAr,r,__hfma2(nAi,i,__hfma2(cBr,sr,__hmul2(nBi,si))));
            pi[k] = __hfma2(cAr,i,__hfma2(cAi,r,__hfma2(cBr,si,__hmul2(cBi,sr))));
        }
    } else if constexpr (P < 11) {
        constexpr int LM = 1 << (P-5);
        int bit = (tid >> (P-5)) & 1;
        float cAr = bit ? m6 : m0, cAi = bit ? m7 : m1;
        float cBr = bit ? m4 : m2, cBi = bit ? m5 : m3;
        H2 a=bc(cAr), ai2=bc(cAi), nai=bc(-cAi), b2=bc(cBr), bi2=bc(cBi), nbi=bc(-cBi);
        #pragma unroll
        for (int k = 0; k < NK; ++k) {
            H2 r = pr[k], i = pi[k];
            H2 qr = shflx(r, LM), qi = shflx(i, LM);
            pr[k] = __hfma2(a,r,__hfma2(nai,i,__hfma2(b2,qr,__hmul2(nbi,qi))));
            pi[k] = __hfma2(a,i,__hfma2(ai2,r,__hfma2(b2,qi,__hmul2(bi2,qr))));
        }
    } else {
        constexpr int WM = 1 << (P-5);
        int ptid = tid ^ WM;
        int bit = (tid >> (P-5)) & 1;
        float cAr = bit ? m6 : m0, cAi = bit ? m7 : m1;
        float cBr = bit ? m4 : m2, cBi = bit ? m5 : m3;
        H2 a=bc(cAr), ai2=bc(cAi), nai=bc(-cAi), b2=bc(cBr), bi2=bc(cBi), nbi=bc(-cBi);
        // half-state per phase (2 F4 pr + 2 F4 pi) -> 32 KB buffer
        #pragma unroll
        for (int h = 0; h < 2; ++h) {
            int base = 8*h;
            buf[0*NT + tid] = make_float4(h2f(pr[base]),  h2f(pr[base+1]),h2f(pr[base+2]),h2f(pr[base+3]));
            buf[1*NT + tid] = make_float4(h2f(pr[base+4]),h2f(pr[base+5]),h2f(pr[base+6]),h2f(pr[base+7]));
            buf[2*NT + tid] = make_float4(h2f(pi[base]),  h2f(pi[base+1]),h2f(pi[base+2]),h2f(pi[base+3]));
            buf[3*NT + tid] = make_float4(h2f(pi[base+4]),h2f(pi[base+5]),h2f(pi[base+6]),h2f(pi[base+7]));
            __syncthreads();
            F4 a0 = buf[0*NT+ptid], a1 = buf[1*NT+ptid];
            F4 b0 = buf[2*NT+ptid], b1 = buf[3*NT+ptid];
            H2 qr[8] = {f2h(a0.x),f2h(a0.y),f2h(a0.z),f2h(a0.w),
                        f2h(a1.x),f2h(a1.y),f2h(a1.z),f2h(a1.w)};
            H2 qi[8] = {f2h(b0.x),f2h(b0.y),f2h(b0.z),f2h(b0.w),
                        f2h(b1.x),f2h(b1.y),f2h(b1.z),f2h(b1.w)};
            #pragma unroll
            for (int q = 0; q < 8; ++q) {
                int k = base + q;
                H2 r = pr[k], i = pi[k];
                pr[k] = __hfma2(a,r,__hfma2(nai,i,__hfma2(b2,qr[q],__hmul2(nbi,qi[q]))));
                pi[k] = __hfma2(a,i,__hfma2(ai2,r,__hfma2(b2,qi[q],__hmul2(bi2,qr[q]))));
            }
            __syncthreads();
        }
    }
}

// ---- CNOT(ctrl bit PC, target bit PT) ----
template<int PC, int PT>
__device__ __forceinline__ void cnot_gate(H2 (&pr)[NK], H2 (&pi)[NK], int tid, F4* buf) {
    if constexpr (PT < 4) {
        constexpr int TM = 1 << PT;
        if constexpr (PC < 4) {
            constexpr int CM = 1 << PC;
            #pragma unroll
            for (int k = 0; k < NK; ++k)
                if ((k & CM) && !(k & TM)) {
                    int k1 = k | TM;
                    H2 t = pr[k]; pr[k] = pr[k1]; pr[k1] = t;
                    t = pi[k]; pi[k] = pi[k1]; pi[k1] = t;
                }
        } else if constexpr (PC == 4) {
            // ctrl = packing bit: swap only hi halves of (k, k|TM)
            #pragma unroll
            for (int k = 0; k < NK; ++k)
                if (!(k & TM)) {
                    int k1 = k | TM;
                    unsigned A = h2u(pr[k]), B = h2u(pr[k1]);
                    pr[k]  = u2h((A & 0xFFFFu) | (B & 0xFFFF0000u));
                    pr[k1] = u2h((B & 0xFFFFu) | (A & 0xFFFF0000u));
                    A = h2u(pi[k]); B = h2u(pi[k1]);
                    pi[k]  = u2h((A & 0xFFFFu) | (B & 0xFFFF0000u));
                    pi[k1] = u2h((B & 0xFFFFu) | (A & 0xFFFF0000u));
                }
        } else {
            int sel = (tid >> (PC-5)) & 1;
            #pragma unroll
            for (int k = 0; k < NK; ++k)
                if (!(k & TM)) {
                    int k1 = k | TM;
                    H2 A = pr[k], B = pr[k1];
                    pr[k] = sel ? B : A; pr[k1] = sel ? A : B;
                    A = pi[k]; B = pi[k1];
                    pi[k] = sel ? B : A; pi[k1] = sel ? A : B;
                }
        }
    } else if constexpr (PT == 4) {
        // target = packing bit: swap halves where ctrl==1
        if constexpr (PC < 4) {
            constexpr int CM = 1 << PC;
            #pragma unroll
            for (int k = 0; k < NK; ++k)
                if (k & CM) {
                    unsigned A = h2u(pr[k]); pr[k] = u2h((A>>16)|(A<<16));
                    A = h2u(pi[k]); pi[k] = u2h((A>>16)|(A<<16));
                }
        } else {
            int sel = (tid >> (PC-5)) & 1;
            #pragma unroll
            for (int k = 0; k < NK; ++k) {
                unsigned A = h2u(pr[k]), S = (A>>16)|(A<<16);
                pr[k] = u2h(sel ? S : A);
                A = h2u(pi[k]); S = (A>>16)|(A<<16);
                pi[k] = u2h(sel ? S : A);
            }
        }
    } else if constexpr (PT < 11) {
        constexpr int LM = 1 << (PT-5);
        if constexpr (PC < 4) {
            constexpr int CM = 1 << PC;
            #pragma unroll
            for (int k = 0; k < NK; ++k)
                if (k & CM) { pr[k] = shflx(pr[k], LM); pi[k] = shflx(pi[k], LM); }
        } else if constexpr (PC == 4) {
            // ctrl = packing bit: only hi halves exchange between partner lanes
            #pragma unroll
            for (int k = 0; k < NK; ++k) {
                unsigned S = h2u(shflx(pr[k], LM));
                pr[k] = u2h((h2u(pr[k]) & 0xFFFFu) | (S & 0xFFFF0000u));
                S = h2u(shflx(pi[k], LM));
                pi[k] = u2h((h2u(pi[k]) & 0xFFFFu) | (S & 0xFFFF0000u));
            }
        } else {
            // ctrl thread bit != PT: partner has same sel -> conditional shuffle
            int sel = (tid >> (PC-5)) & 1;
            #pragma unroll
            for (int k = 0; k < NK; ++k) {
                H2 sr = shflx(pr[k], LM), si = shflx(pi[k], LM);
                pr[k] = sel ? sr : pr[k];
                pi[k] = sel ? si : pi[k];
            }
        }
    } else {
        constexpr int WM = 1 << (PT-5);
        int ptid = tid ^ WM;
        if constexpr (PC < 4) {
            constexpr int CM = 1 << PC;
            // exchange only the 8 ctrl==1 regs (2 F4 pr + 2 F4 pi), one phase
            H2 vr[8], vi[8];
            { int c = 0;
              #pragma unroll
              for (int k = 0; k < NK; ++k)
                  if (k & CM) { vr[c]=pr[k]; vi[c]=pi[k]; ++c; } }
            buf[0*NT+tid] = make_float4(h2f(vr[0]),h2f(vr[1]),h2f(vr[2]),h2f(vr[3]));
            buf[1*NT+tid] = make_float4(h2f(vr[4]),h2f(vr[5]),h2f(vr[6]),h2f(vr[7]));
            buf[2*NT+tid] = make_float4(h2f(vi[0]),h2f(vi[1]),h2f(vi[2]),h2f(vi[3]));
            buf[3*NT+tid] = make_float4(h2f(vi[4]),h2f(vi[5]),h2f(vi[6]),h2f(vi[7]));
            __syncthreads();
            F4 a0 = buf[0*NT+ptid], a1 = buf[1*NT+ptid];
            F4 b0 = buf[2*NT+ptid], b1 = buf[3*NT+ptid];
            H2 wr[8] = {f2h(a0.x),f2h(a0.y),f2h(a0.z),f2h(a0.w),
                        f2h(a1.x),f2h(a1.y),f2h(a1.z),f2h(a1.w)};
            H2 wi[8] = {f2h(b0.x),f2h(b0.y),f2h(b0.z),f2h(b0.w),
                        f2h(b1.x),f2h(b1.y),f2h(b1.z),f2h(b1.w)};
            { int c = 0;
              #pragma unroll
              for (int k = 0; k < NK; ++k)
                  if (k & CM) { pr[k]=wr[c]; pi[k]=wi[c]; ++c; } }
            __syncthreads();
        } else if constexpr (PC == 4) {
            // ctrl = packing bit: hi halves exchange with partner thread (4 F4)
            unsigned er[8], ei[8];
            #pragma unroll
            for (int t = 0; t < 8; ++t) {
                er[t] = (h2u(pr[2*t]) >> 16) | (h2u(pr[2*t+1]) & 0xFFFF0000u);
                ei[t] = (h2u(pi[2*t]) >> 16) | (h2u(pi[2*t+1]) & 0xFFFF0000u);
            }
            buf[0*NT+tid] = make_float4(uf(er[0]),uf(er[1]),uf(er[2]),uf(er[3]));
            buf[1*NT+tid] = make_float4(uf(er[4]),uf(er[5]),uf(er[6]),uf(er[7]));
            buf[2*NT+tid] = make_float4(uf(ei[0]),uf(ei[1]),uf(ei[2]),uf(ei[3]));
            buf[3*NT+tid] = make_float4(uf(ei[4]),uf(ei[5]),uf(ei[6]),uf(ei[7]));
            __syncthreads();
            F4 a0 = buf[0*NT+ptid], a1 = buf[1*NT+ptid];
            F4 b0 = buf[2*NT+ptid], b1 = buf[3*NT+ptid];
            unsigned fr[8] = {fu(a0.x),fu(a0.y),fu(a0.z),fu(a0.w),
                              fu(a1.x),fu(a1.y),fu(a1.z),fu(a1.w)};
            unsigned fi[8] = {fu(b0.x),fu(b0.y),fu(b0.z),fu(b0.w),
                              fu(b1.x),fu(b1.y),fu(b1.z),fu(b1.w)};
            #pragma unroll
            for (int t = 0; t < 8; ++t) {
                pr[2*t]   = u2h((h2u(pr[2*t])   & 0xFFFFu) | (fr[t] << 16));
                pr[2*t+1] = u2h((h2u(pr[2*t+1]) & 0xFFFFu) | (fr[t] & 0xFFFF0000u));
                pi[2*t]   = u2h((h2u(pi[2*t])   & 0xFFFFu) | (fi[t] << 16));
                pi[2*t+1] = u2h((h2u(pi[2*t+1]) & 0xFFFFu) | (fi[t] & 0xFFFF0000u));
            }
            __syncthreads();
        } else {
            // ctrl thread bit != PT: sel==1 threads swap full state, 2 half phases
            int sel = (tid >> (PC-5)) & 1;
            #pragma unroll
            for (int h = 0; h < 2; ++h) {
                int base = 8*h;
                if (sel) {
                    buf[0*NT+tid] = make_float4(h2f(pr[base]),  h2f(pr[base+1]),h2f(pr[base+2]),h2f(pr[base+3]));
                    buf[1*NT+tid] = make_float4(h2f(pr[base+4]),h2f(pr[base+5]),h2f(pr[base+6]),h2f(pr[base+7]));
                    buf[2*NT+tid] = make_float4(h2f(pi[base]),  h2f(pi[base+1]),h2f(pi[base+2]),h2f(pi[base+3]));
                    buf[3*NT+tid] = make_float4(h2f(pi[base+4]),h2f(pi[base+5]),h2f(pi[base+6]),h2f(pi[base+7]));
                }
                __syncthreads();
                if (sel) {
                    F4 a0 = buf[0*NT+ptid], a1 = buf[1*NT+ptid];
                    F4 b0 = buf[2*NT+ptid], b1 = buf[3*NT+ptid];
                    pr[base]  =f2h(a0.x); pr[base+1]=f2h(a0.y); pr[base+2]=f2h(a0.z); pr[base+3]=f2h(a0.w);
                    pr[base+4]=f2h(a1.x); pr[base+5]=f2h(a1.y); pr[base+6]=f2h(a1.z); pr[base+7]=f2h(a1.w);
                    pi[base]  =f2h(b0.x); pi[base+1]=f2h(b0.y); pi[base+2]=f2h(b0.z); pi[base+3]=f2h(b0.w);
                    pi[base+4]=f2h(b1.x); pi[base+5]=f2h(b1.y); pi[base+6]=f2h(b1.z); pi[base+7]=f2h(b1.w);
                }
                __syncthreads();
            }
        }
    }
}

// ---- compile-time circuit drivers ----
template<int L, int W>
__device__ __forceinline__ void do_rots(H2 (&pr)[NK], H2 (&pi)[NK],
                                        const float* __restrict__ gm, int tid, F4* buf) {
    rot_gate<13-W>(pr, pi, gm + (L*NQ + W)*8, tid, buf);
    if constexpr (W < NQ-1) do_rots<L, W+1>(pr, pi, gm, tid, buf);
}

template<int L, int W>
__device__ __forceinline__ void do_cnots(H2 (&pr)[NK], H2 (&pi)[NK], int tid, F4* buf) {
    constexpr int R = (L % (NQ-1)) + 1;
    constexpr int TW = (W + R) % NQ;
    cnot_gate<13-W, 13-TW>(pr, pi, tid, buf);
    if constexpr (W < NQ-1) do_cnots<L, W+1>(pr, pi, tid, buf);
}

template<int L>
__device__ __forceinline__ void do_layer(H2 (&pr)[NK], H2 (&pi)[NK],
                                         const float* __restrict__ gm, int tid, F4* buf) {
    do_rots<L, 0>(pr, pi, gm, tid, buf);
    do_cnots<L, 0>(pr, pi, tid, buf);
    if constexpr (L < NL-1) do_layer<L+1>(pr, pi, gm, tid, buf);
}

__global__ void __launch_bounds__(NT)
qsim_kernel(
    const float* __restrict__ x,
    const float* __restrict__ gm,
    float* __restrict__ out)
{
    __shared__ F4 buf[4 * NT];   // static 32 KB -> 4 blocks/CU
    const int tid = threadIdx.x;
    const int b = blockIdx.x;
    const float* xb = x + b * NQ;

    // ---- direct product-state init (fp32 math, pack to fp16) ----
    H2 pr[NK], pi[NK];
    {
        float cr = 1.f, ci = 0.f;
        #pragma unroll
        for (int bb = 0; bb < 9; ++bb) {       // tid bit bb = amp bit 5+bb = wire 8-bb
            float t = xb[8 - bb];
            float c = cosf(0.5f*t), s = sinf(0.5f*t);
            if ((tid >> bb) & 1) { float nr = s*ci, ni = -s*cr; cr = nr; ci = ni; }
            else                 { cr *= c; ci *= c; }
        }
        float lc[4], ls[4];                     // k bit bb = wire 13-bb
        #pragma unroll
        for (int bb = 0; bb < 4; ++bb) {
            float t = xb[13 - bb];
            lc[bb] = cosf(0.5f*t); ls[bb] = sinf(0.5f*t);
        }
        float c9 = cosf(0.5f*xb[9]), s9 = sinf(0.5f*xb[9]);   // packing bit = wire 9
        #pragma unroll
        for (int k = 0; k < NK; ++k) {
            float rr = cr, ii = ci;
            #pragma unroll
            for (int bb = 0; bb < 4; ++bb) {
                if ((k >> bb) & 1) { float nr = ls[bb]*ii, ni = -ls[bb]*rr; rr = nr; ii = ni; }
                else               { rr *= lc[bb]; ii *= lc[bb]; }
            }
            pr[k] = __floats2half2_rn(rr*c9,  s9*ii);
            pi[k] = __floats2half2_rn(ii*c9, -s9*rr);
        }
    }
    __syncthreads();

    do_layer<0>(pr, pi, gm, tid, buf);

    // <Z0>: amp bit 13 = tid bit 8 -> sign uniform per thread
    float acc = 0.f;
    #pragma unroll
    for (int k = 0; k < NK; ++k) {
        float a=__low2float(pr[k]), c=__high2float(pr[k]);
        float d=__low2float(pi[k]), e=__high2float(pi[k]);
        acc += a*a + c*c + d*d + e*e;
    }
    if (tid & 256) acc = -acc;
    #pragma unroll
    for (int off = 32; off > 0; off >>= 1) acc += __shfl_down(acc, off, 64);
    __syncthreads();
    float* f = (float*)buf;
    if ((tid & 63) == 0) f[tid >> 6] = acc;
    __syncthreads();
    if (tid == 0) {
        float s = 0.f;
        #pragma unroll
        for (int w = 0; w < NT/64; ++w) s += f[w];
        out[b] = s;
    }
}

extern "C" void kernel_launch(void* const* d_in, const int* in_sizes, int n_in,
                              void* d_out, int out_size, void* d_ws, size_t ws_size,
                              hipStream_t stream) {
    const float* x = (const float*)d_in[0];   // (1024, 14) float32
    const float* w = (const float*)d_in[1];   // (6, 14, 3) float32
    float* out = (float*)d_out;               // (1024,) float32
    float* gm = (float*)d_ws;                 // 84*8 floats of Rot matrices

    prep_kernel<<<1, 128, 0, stream>>>(w, gm);
    qsim_kernel<<<out_size, NT, 0, stream>>>(x, gm, out);
}

// Round 19
// 307.479 us; speedup vs baseline: 1.2789x; 1.2452x over previous
//
#include <hip/hip_runtime.h>
#include <hip/hip_fp16.h>
#include <math.h>

#define NQ 14
#define NL 6
#define NT 512
#define NGATES (NL * NQ)
#define NK 16   // half2 regs per re/im = 32 amps/thread
// amp p = (tid<<5) | j, j=0..31. j bits 0-3 = reg k, j bit 4 = packing bit.
// amp bit map: p<4 local k-bit; p==4 packing; 5<=p<11 lane bit (tid bit p-5);
// p>=11 wave bit (tid bits 6..8). Wire w <-> P = 13-w.
// R19: each layer's 14-CNOT ring is a GF(2)-LINEAR index permutation F_l
// (CNOT: i -> i ^ (bit_c(i)<<t) is linear; composition stays linear).
// Apply the whole ring as ONE LDS scatter: write amp p to swiz(F(p)), read
// from swiz(p). 64 b32 DS ops + 2 barriers replace ~14 gates. The LAST
// layer's ring is never materialized: measurement sign = bit13 of F5(p).
// 64 KB buffer (full-state single-phase wave rots, 2 blocks/CU).

using F4 = float4;
using H2 = __half2;

__device__ __forceinline__ unsigned h2u(H2 v){ return __builtin_bit_cast(unsigned, v); }
__device__ __forceinline__ H2 u2h(unsigned x){ return __builtin_bit_cast(H2, x); }
__device__ __forceinline__ float h2f(H2 v){ return __builtin_bit_cast(float, v); }
__device__ __forceinline__ H2 f2h(float x){ return __builtin_bit_cast(H2, x); }
__device__ __forceinline__ H2 bc(float x){ return __float2half2_rn(x); }
__device__ __forceinline__ H2 shflx(H2 v, int m){
    return u2h((unsigned)__shfl_xor((int)h2u(v), m, 64));
}

// image of index v under layer-l CNOT ring (gate order w=0..13) — GF(2)-linear
__device__ constexpr int ring_F(int l, int v) {
    int r = (l % 13) + 1;
    for (int w = 0; w < NQ; ++w) {
        int pc = 13 - w, pt = 13 - ((w + r) % NQ);
        v ^= ((v >> pc) & 1) << pt;
    }
    return v;
}

// ---- prep: Rot matrices (batch-shared, fp32) into d_ws ----
__global__ void prep_kernel(const float* __restrict__ wts, float* __restrict__ gm) {
    int g = blockIdx.x * blockDim.x + threadIdx.x;
    if (g < NGATES) {
        float phi = wts[g*3+0], th = wts[g*3+1], om = wts[g*3+2];
        float c = cosf(0.5f*th), s = sinf(0.5f*th);
        float a = 0.5f*(phi+om), bb = 0.5f*(phi-om);
        float ca = cosf(a), sa = sinf(a);
        float cb = cosf(bb), sb = sinf(bb);
        gm[g*8+0] = c*ca;  gm[g*8+1] = -c*sa;   // m00
        gm[g*8+2] = -s*cb; gm[g*8+3] = -s*sb;   // m01
        gm[g*8+4] = s*cb;  gm[g*8+5] = -s*sb;   // m10
        gm[g*8+6] = c*ca;  gm[g*8+7] = c*sa;    // m11
    }
}

// ---- Rot on amp bit P ----
template<int P>
__device__ __forceinline__ void rot_gate(H2 (&pr)[NK], H2 (&pi)[NK],
                                         const float* __restrict__ m, int tid, F4* buf) {
    float m0=m[0],m1=m[1],m2=m[2],m3=m[3],m4=m[4],m5=m[5],m6=m[6],m7=m[7];
    if constexpr (P < 4) {
        constexpr int M = 1 << P;
        H2 h0=bc(m0),h1=bc(m1),nh1=bc(-m1),h2v=bc(m2),h3=bc(m3),nh3=bc(-m3);
        H2 h4=bc(m4),h5=bc(m5),nh5=bc(-m5),h6=bc(m6),h7=bc(m7),nh7=bc(-m7);
        #pragma unroll
        for (int i = 0; i < NK/2; ++i) {
            int k0 = ((i >> P) << (P+1)) | (i & (M-1));
            int k1 = k0 | M;
            H2 r0=pr[k0], i0=pi[k0], r1=pr[k1], i1=pi[k1];
            pr[k0] = __hfma2(h0,r0,__hfma2(nh1,i0,__hfma2(h2v,r1,__hmul2(nh3,i1))));
            pi[k0] = __hfma2(h0,i0,__hfma2(h1,r0,__hfma2(h2v,i1,__hmul2(h3,r1))));
            pr[k1] = __hfma2(h4,r0,__hfma2(nh5,i0,__hfma2(h6,r1,__hmul2(nh7,i1))));
            pi[k1] = __hfma2(h4,i0,__hfma2(h5,r0,__hfma2(h6,i1,__hmul2(h7,r1))));
        }
    } else if constexpr (P == 4) {
        // packing-bit rot, fully packed: half-swap + per-half coeff H2s
        H2 cAr = __floats2half2_rn(m0, m6), cAi = __floats2half2_rn(m1, m7);
        H2 nAi = __floats2half2_rn(-m1,-m7);
        H2 cBr = __floats2half2_rn(m2, m4), cBi = __floats2half2_rn(m3, m5);
        H2 nBi = __floats2half2_rn(-m3,-m5);
        #pragma unroll
        for (int k = 0; k < NK; ++k) {
            unsigned Ar = h2u(pr[k]), Ai = h2u(pi[k]);
            H2 sr = u2h((Ar>>16)|(Ar<<16)), si = u2h((Ai>>16)|(Ai<<16));
            H2 r = pr[k], i = pi[k];
            pr[k] = __hfma2(cAr,r,__hfma2(nAi,i,__hfma2(cBr,sr,__hmul2(nBi,si))));
            pi[k] = __hfma2(cAr,i,__hfma2(cAi,r,__hfma2(cBr,si,__hmul2(cBi,sr))));
        }
    } else if constexpr (P < 11) {
        constexpr int LM = 1 << (P-5);
        int bit = (tid >> (P-5)) & 1;
        float cAr = bit ? m6 : m0, cAi = bit ? m7 : m1;
        float cBr = bit ? m4 : m2, cBi = bit ? m5 : m3;
        H2 a=bc(cAr), ai2=bc(cAi), nai=bc(-cAi), b2=bc(cBr), bi2=bc(cBi), nbi=bc(-cBi);
        #pragma unroll
        for (int k = 0; k < NK; ++k) {
            H2 r = pr[k], i = pi[k];
            H2 qr = shflx(r, LM), qi = shflx(i, LM);
            pr[k] = __hfma2(a,r,__hfma2(nai,i,__hfma2(b2,qr,__hmul2(nbi,qi))));
            pi[k] = __hfma2(a,i,__hfma2(ai2,r,__hfma2(b2,qi,__hmul2(bi2,qr))));
        }
    } else {
        constexpr int WM = 1 << (P-5);
        int ptid = tid ^ WM;
        int bit = (tid >> (P-5)) & 1;
        float cAr = bit ? m6 : m0, cAi = bit ? m7 : m1;
        float cBr = bit ? m4 : m2, cBi = bit ? m5 : m3;
        H2 a=bc(cAr), ai2=bc(cAi), nai=bc(-cAi), b2=bc(cBr), bi2=bc(cBi), nbi=bc(-cBi);
        // full state (4 F4 pr + 4 F4 pi) in one phase, 64 KB buffer
        #pragma unroll
        for (int q = 0; q < 4; ++q) {
            int k = 4*q;
            buf[q*NT + tid]     = make_float4(h2f(pr[k]),h2f(pr[k+1]),h2f(pr[k+2]),h2f(pr[k+3]));
            buf[(4+q)*NT + tid] = make_float4(h2f(pi[k]),h2f(pi[k+1]),h2f(pi[k+2]),h2f(pi[k+3]));
        }
        __syncthreads();
        H2 qr[NK], qi[NK];
        #pragma unroll
        for (int q = 0; q < 4; ++q) {
            F4 xr = buf[q*NT + ptid];
            qr[4*q]=f2h(xr.x); qr[4*q+1]=f2h(xr.y); qr[4*q+2]=f2h(xr.z); qr[4*q+3]=f2h(xr.w);
        }
        #pragma unroll
        for (int q = 0; q < 4; ++q) {
            F4 xi = buf[(4+q)*NT + ptid];
            qi[4*q]=f2h(xi.x); qi[4*q+1]=f2h(xi.y); qi[4*q+2]=f2h(xi.z); qi[4*q+3]=f2h(xi.w);
        }
        #pragma unroll
        for (int k = 0; k < NK; ++k) {
            H2 r = pr[k], i = pi[k];
            pr[k] = __hfma2(a,r,__hfma2(nai,i,__hfma2(b2,qr[k],__hmul2(nbi,qi[k]))));
            pi[k] = __hfma2(a,i,__hfma2(ai2,r,__hfma2(b2,qi[k],__hmul2(bi2,qr[k]))));
        }
        __syncthreads();
    }
}

// ---- whole CNOT ring of layer L as one LDS permutation ----
// scatter: amp p -> LDS[swiz(F(p))]; gather own slots swiz(p).
// swiz(p) = p ^ ((p>>5)&31) -> read side conflict-free.
template<int L>
__device__ __forceinline__ void perm_exchange(H2 (&pr)[NK], H2 (&pi)[NK],
                                              int tid, F4* buf) {
    unsigned* ub = (unsigned*)buf;
    int base = ring_F(L, tid << 5);   // linear: F(p) = F(tid<<5) ^ F(j)
    #pragma unroll
    for (int k = 0; k < NK; ++k) {
        unsigned wlo = (h2u(pr[k]) & 0xFFFFu) | (h2u(pi[k]) << 16);      // amp j=k
        unsigned whi = (h2u(pr[k]) >> 16) | (h2u(pi[k]) & 0xFFFF0000u);  // amp j=k|16
        int flo = base ^ ring_F(L, k);
        int fhi = base ^ ring_F(L, k | 16);
        ub[flo ^ ((flo >> 5) & 31)] = wlo;
        ub[fhi ^ ((fhi >> 5) & 31)] = whi;
    }
    __syncthreads();
    int sw = tid & 31;
    #pragma unroll
    for (int k = 0; k < NK; ++k) {
        unsigned wlo = ub[((tid << 5) | k) ^ sw];
        unsigned whi = ub[((tid << 5) | (k | 16)) ^ sw];
        pr[k] = u2h((wlo & 0xFFFFu) | (whi << 16));
        pi[k] = u2h((wlo >> 16) | (whi & 0xFFFF0000u));
    }
    __syncthreads();
}

// ---- compile-time circuit drivers ----
template<int L, int W>
__device__ __forceinline__ void do_rots(H2 (&pr)[NK], H2 (&pi)[NK],
                                        const float* __restrict__ gm, int tid, F4* buf) {
    rot_gate<13-W>(pr, pi, gm + (L*NQ + W)*8, tid, buf);
    if constexpr (W < NQ-1) do_rots<L, W+1>(pr, pi, gm, tid, buf);
}

template<int L>
__device__ __forceinline__ void do_layer(H2 (&pr)[NK], H2 (&pi)[NK],
                                         const float* __restrict__ gm, int tid, F4* buf) {
    do_rots<L, 0>(pr, pi, gm, tid, buf);
    if constexpr (L < NL-1) {
        perm_exchange<L>(pr, pi, tid, buf);   // last layer's ring folded into sign
        do_layer<L+1>(pr, pi, gm, tid, buf);
    }
}

__global__ void __launch_bounds__(NT)
qsim_kernel(
    const float* __restrict__ x,
    const float* __restrict__ gm,
    float* __restrict__ out)
{
    __shared__ F4 buf[8 * NT];   // static 64 KB -> 2 blocks/CU
    const int tid = threadIdx.x;
    const int b = blockIdx.x;
    const float* xb = x + b * NQ;

    // ---- direct product-state init (fp32 math, pack to fp16) ----
    H2 pr[NK], pi[NK];
    {
        float cr = 1.f, ci = 0.f;
        #pragma unroll
        for (int bb = 0; bb < 9; ++bb) {       // tid bit bb = amp bit 5+bb = wire 8-bb
            float t = xb[8 - bb];
            float c = cosf(0.5f*t), s = sinf(0.5f*t);
            if ((tid >> bb) & 1) { float nr = s*ci, ni = -s*cr; cr = nr; ci = ni; }
            else                 { cr *= c; ci *= c; }
        }
        float lc[4], ls[4];                     // k bit bb = wire 13-bb
        #pragma unroll
        for (int bb = 0; bb < 4; ++bb) {
            float t = xb[13 - bb];
            lc[bb] = cosf(0.5f*t); ls[bb] = sinf(0.5f*t);
        }
        float c9 = cosf(0.5f*xb[9]), s9 = sinf(0.5f*xb[9]);   // packing bit = wire 9
        #pragma unroll
        for (int k = 0; k < NK; ++k) {
            float rr = cr, ii = ci;
            #pragma unroll
            for (int bb = 0; bb < 4; ++bb) {
                if ((k >> bb) & 1) { float nr = ls[bb]*ii, ni = -ls[bb]*rr; rr = nr; ii = ni; }
                else               { rr *= lc[bb]; ii *= lc[bb]; }
            }
            pr[k] = __floats2half2_rn(rr*c9,  s9*ii);
            pi[k] = __floats2half2_rn(ii*c9, -s9*rr);
        }
    }
    __syncthreads();

    do_layer<0>(pr, pi, gm, tid, buf);

    // ---- <Z0>: last ring skipped; sign = bit13 of F5(p), per amp ----
    int base5 = ring_F(NL-1, tid << 5);
    float acc = 0.f;
    #pragma unroll
    for (int k = 0; k < NK; ++k) {
        float a=__low2float(pr[k]), c=__high2float(pr[k]);
        float d=__low2float(pi[k]), e=__high2float(pi[k]);
        float vlo = a*a + d*d, vhi = c*c + e*e;
        int slo = (base5 ^ ring_F(NL-1, k))      & (1 << 13);
        int shi = (base5 ^ ring_F(NL-1, k | 16)) & (1 << 13);
        acc += slo ? -vlo : vlo;
        acc += shi ? -vhi : vhi;
    }
    #pragma unroll
    for (int off = 32; off > 0; off >>= 1) acc += __shfl_down(acc, off, 64);
    __syncthreads();
    float* f = (float*)buf;
    if ((tid & 63) == 0) f[tid >> 6] = acc;
    __syncthreads();
    if (tid == 0) {
        float s = 0.f;
        #pragma unroll
        for (int w = 0; w < NT/64; ++w) s += f[w];
        out[b] = s;
    }
}

extern "C" void kernel_launch(void* const* d_in, const int* in_sizes, int n_in,
                              void* d_out, int out_size, void* d_ws, size_t ws_size,
                              hipStream_t stream) {
    const float* x = (const float*)d_in[0];   // (1024, 14) float32
    const float* w = (const float*)d_in[1];   // (6, 14, 3) float32
    float* out = (float*)d_out;               // (1024,) float32
    float* gm = (float*)d_ws;                 // 84*8 floats of Rot matrices

    prep_kernel<<<1, 128, 0, stream>>>(w, gm);
    qsim_kernel<<<out_size, NT, 0, stream>>>(x, gm, out);
}